// Round 3
// baseline (196.940 us; speedup 1.0000x reference)
//
#include <hip/hip_runtime.h>
#include <hip/hip_bf16.h>

// TreeCNN on MI355X — bf16 MFMA, fused BN-finalize prologues, fused tree-sums.
// B=256 trees, 2048->256->32->1 (arities 8,8,32), D_IN=128, HID=256, OUT=10.
// 12 dispatches: memset, prep_weights, pool8(+ts0), G1a, G1b(BN), pool8h(+ts1),
// G2a, G2b(BN), pool32, G3a, G3b(BN), head.

#define N0 (256*2048)
#define N1 (256*256)
#define N2 (256*32)
#define NB 256
#define BN_EPS 1e-5f
#define NSLOT 8

typedef __attribute__((ext_vector_type(8))) __bf16 bf16x8;
typedef __attribute__((ext_vector_type(8))) unsigned short u16x8;
typedef __attribute__((ext_vector_type(4))) unsigned short u16x4;
typedef __attribute__((ext_vector_type(4))) float f32x4;

__device__ inline float bf2f(unsigned short b) {
    unsigned u = ((unsigned)b) << 16;
    float f; __builtin_memcpy(&f, &u, 4); return f;
}
__device__ inline unsigned short f2bf(float f) {
    unsigned u; __builtin_memcpy(&u, &f, 4);
    u += 0x7fff + ((u >> 16) & 1);
    return (unsigned short)(u >> 16);
}

// ---------- weights: transpose + f32->bf16, Wt[n][k] ----------
__global__ __launch_bounds__(256) void prep_weights(const float* __restrict__ l1_w1,
                                                    const float* __restrict__ l1_w2,
                                                    const float* __restrict__ lw1,
                                                    const float* __restrict__ lw2,
                                                    unsigned short* __restrict__ Wt) {
    int idx = blockIdx.x * 256 + threadIdx.x;
    if (idx >= 360448) return;
    float v;
    if (idx < 32768) {                       // l1_w1 [128,256] -> [256][128]
        int n = idx >> 7, k = idx & 127;
        v = l1_w1[k * 256 + n];
    } else if (idx < 98304) {                // l1_w2 [256,256]
        int j = idx - 32768, n = j >> 8, k = j & 255;
        v = l1_w2[k * 256 + n];
    } else if (idx < 163840) {               // lw1[0]
        int j = idx - 98304, n = j >> 8, k = j & 255;
        v = lw1[k * 256 + n];
    } else if (idx < 229376) {               // lw2[0]
        int j = idx - 163840, n = j >> 8, k = j & 255;
        v = lw2[k * 256 + n];
    } else if (idx < 294912) {               // lw1[1]
        int j = idx - 229376, n = j >> 8, k = j & 255;
        v = lw1[65536 + k * 256 + n];
    } else {                                 // lw2[1]
        int j = idx - 294912, n = j >> 8, k = j & 255;
        v = lw2[65536 + k * 256 + n];
    }
    Wt[idx] = f2bf(v);
}

// ---------- BN finalize prologue helper (256 threads compute scale/shift in LDS) ----------
__device__ inline void bn_prologue(int tid, const float* __restrict__ partials,
                                   const float* __restrict__ g, const float* __restrict__ b,
                                   float invM, float* sc_lds, float* sh_lds) {
    if (tid < 256) {
        float s = 0.f, s2 = 0.f;
#pragma unroll
        for (int k = 0; k < NSLOT; ++k) {
            s  += partials[k * 512 + tid];
            s2 += partials[k * 512 + 256 + tid];
        }
        float mean = s * invM;
        float var = s2 * invM - mean * mean;
        float sc = g[tid] * rsqrtf(var + BN_EPS);
        sc_lds[tid] = sc;
        sh_lds[tid] = b[tid] - mean * sc;
    }
}

// ---------- x (f32) -> pooled1 (bf16) group-8 sum + fused ts0 (per-tree sums) ----------
__global__ __launch_bounds__(256) void pool8_128(const float* __restrict__ x,
                                                 unsigned short* __restrict__ out,
                                                 float* __restrict__ ts0) {
    int tid = threadIdx.x;
    int c4 = tid & 31, pl = tid >> 5;        // 8 pooled rows per block
    int p = blockIdx.x * 8 + pl;
    int tree = blockIdx.x >> 5;              // 32 blocks per tree
    const f32x4* xp = reinterpret_cast<const f32x4*>(x + (size_t)p * 8 * 128 + c4 * 4);
    f32x4 s = {0.f, 0.f, 0.f, 0.f};
#pragma unroll
    for (int c = 0; c < 8; ++c) s += xp[c * 32];
    u16x4 o;
#pragma unroll
    for (int e = 0; e < 4; ++e) o[e] = f2bf(s[e]);
    *reinterpret_cast<u16x4*>(out + (size_t)p * 128 + c4 * 4) = o;
    // ts0 partial: reduce the 8 rows of this block, one atomicAdd per column
    __shared__ float red[4][32][4];
    int w = tid >> 6;
    f32x4 t = s;
#pragma unroll
    for (int e = 0; e < 4; ++e) t[e] += __shfl_xor(t[e], 32);
    if ((tid & 63) < 32) {
#pragma unroll
        for (int e = 0; e < 4; ++e) red[w][c4][e] = t[e];
    }
    __syncthreads();
    if (tid < 128) {
        int cc = tid >> 2, e = tid & 3;
        float v = red[0][cc][e] + red[1][cc][e] + red[2][cc][e] + red[3][cc][e];
        atomicAdd(&ts0[tree * 128 + tid], v);
    }
}

// ---------- pooled = group-sum of relu(scale*Z+shift); BN prologue; optional ts ----------
template <int GROUP, bool TS>
__global__ __launch_bounds__(256) void pool_bn_relu(const unsigned short* __restrict__ Z,
                                                    const float* __restrict__ partials,
                                                    const float* __restrict__ g,
                                                    const float* __restrict__ b,
                                                    float invM,
                                                    unsigned short* __restrict__ out,
                                                    float* __restrict__ ts) {
    __shared__ float sc_lds[256], sh_lds[256];
    int tid = threadIdx.x;
    bn_prologue(tid, partials, g, b, invM, sc_lds, sh_lds);
    __syncthreads();
    int c8 = tid & 31, pl = tid >> 5;        // 8 out-rows per block, 8 cols per thread
    size_t p = (size_t)blockIdx.x * 8 + pl;
    int d0 = c8 * 8;
    float sc[8], sh[8], s[8];
#pragma unroll
    for (int e = 0; e < 8; ++e) { sc[e] = sc_lds[d0 + e]; sh[e] = sh_lds[d0 + e]; s[e] = 0.f; }
#pragma unroll
    for (int gi = 0; gi < GROUP; ++gi) {
        u16x8 z = *reinterpret_cast<const u16x8*>(Z + (p * GROUP + gi) * 256 + d0);
#pragma unroll
        for (int e = 0; e < 8; ++e) {
            float f = sc[e] * bf2f(z[e]) + sh[e];
            s[e] += f > 0.f ? f : 0.f;
        }
    }
    u16x8 o;
#pragma unroll
    for (int e = 0; e < 8; ++e) o[e] = f2bf(s[e]);
    *reinterpret_cast<u16x8*>(out + p * 256 + d0) = o;
    if (TS) {
        // per-tree sum of the block's 8 output rows (32 rows/tree -> 4 blocks/tree)
        __shared__ float red[4][32][8];
        int tree = blockIdx.x >> 2;
        int w = tid >> 6;
#pragma unroll
        for (int e = 0; e < 8; ++e) s[e] += __shfl_xor(s[e], 32);
        if ((tid & 63) < 32) {
#pragma unroll
            for (int e = 0; e < 8; ++e) red[w][c8][e] = s[e];
        }
        __syncthreads();
        {
            int cc = tid >> 3, e = tid & 7;
            float v = red[0][cc][e] + red[1][cc][e] + red[2][cc][e] + red[3][cc][e];
            atomicAdd(&ts[tree * 256 + tid], v);
        }
    }
}

// ---------- MFMA GEMM: C[M,256](bf16) = f(A[M,K]) @ Wt^T + bias; col-stats fused ----------
// f = identity or relu(scale[k]*a+shift[k]) with scale/shift computed in prologue.
// Block: BM rows x 256 cols; BM/16 waves of 64 lanes; wave (wr,wc) owns 64x64.
template <int KD, bool BN_A, int BM>
__global__ __launch_bounds__(BM * 4) void mfma_gemm(const unsigned short* __restrict__ A,
                                                    const float* __restrict__ partials_in,
                                                    const float* __restrict__ bn_g,
                                                    const float* __restrict__ bn_b,
                                                    float invM,
                                                    const unsigned short* __restrict__ Wt,
                                                    const float* __restrict__ bias,
                                                    unsigned short* __restrict__ C,
                                                    float* __restrict__ stat_partials) {
    constexpr int LDA = 72;                  // padded bf16 row stride
    constexpr int NT = BM * 4;
    __shared__ unsigned short Asb[BM * LDA];
    __shared__ unsigned short Bsb[256 * LDA];
    __shared__ float sc_lds[256], sh_lds[256];
    const int tid = threadIdx.x;
    if (BN_A) {
        bn_prologue(tid, partials_in, bn_g, bn_b, invM, sc_lds, sh_lds);
        __syncthreads();
    }
    const int m0 = blockIdx.x * BM;
    const int wave = tid >> 6, lane = tid & 63;
    const int q = lane >> 4, r = lane & 15;
    const int wc = wave & 3, wr = wave >> 2;

    f32x4 acc[4][4];
#pragma unroll
    for (int i = 0; i < 4; ++i)
#pragma unroll
        for (int j = 0; j < 4; ++j) acc[i][j] = (f32x4){0.f, 0.f, 0.f, 0.f};

    for (int k0 = 0; k0 < KD; k0 += 64) {
        // stage A tile: BM rows x 64 k
#pragma unroll
        for (int i = 0; i < 2; ++i) {
            int v = tid + i * NT;
            int row = v >> 3, kc = v & 7;
            u16x8 d = *reinterpret_cast<const u16x8*>(A + (size_t)(m0 + row) * KD + k0 + kc * 8);
            if (BN_A) {
                u16x8 o;
#pragma unroll
                for (int e = 0; e < 8; ++e) {
                    int k = k0 + kc * 8 + e;
                    float f = sc_lds[k] * bf2f(d[e]) + sh_lds[k];
                    o[e] = f2bf(f > 0.f ? f : 0.f);
                }
                d = o;
            }
            *reinterpret_cast<u16x8*>(&Asb[row * LDA + kc * 8]) = d;
        }
        // stage B tile: 256 n x 64 k (n-major Wt)
#pragma unroll
        for (int i = 0; i < 2048 / NT; ++i) {
            int v = tid + i * NT;
            int n = v >> 3, kc = v & 7;
            u16x8 d = *reinterpret_cast<const u16x8*>(Wt + (size_t)n * KD + k0 + kc * 8);
            *reinterpret_cast<u16x8*>(&Bsb[n * LDA + kc * 8]) = d;
        }
        __syncthreads();
#pragma unroll
        for (int s = 0; s < 2; ++s) {
            bf16x8 a[4], b[4];
#pragma unroll
            for (int i = 0; i < 4; ++i)
                a[i] = *reinterpret_cast<const bf16x8*>(&Asb[(wr * 64 + i * 16 + r) * LDA + s * 32 + q * 8]);
#pragma unroll
            for (int j = 0; j < 4; ++j)
                b[j] = *reinterpret_cast<const bf16x8*>(&Bsb[(wc * 64 + j * 16 + r) * LDA + s * 32 + q * 8]);
#pragma unroll
            for (int i = 0; i < 4; ++i)
#pragma unroll
                for (int j = 0; j < 4; ++j)
                    acc[i][j] = __builtin_amdgcn_mfma_f32_16x16x32_bf16(a[i], b[j], acc[i][j], 0, 0, 0);
        }
        __syncthreads();
    }

    // epilogue: +bias, column stats, bf16 store. C/D: col=r, row=q*4+e (per 16x16).
    float sj[4], s2j[4];
#pragma unroll
    for (int j = 0; j < 4; ++j) {
        float bj = bias[wc * 64 + j * 16 + r];
        float s = 0.f, s2 = 0.f;
#pragma unroll
        for (int i = 0; i < 4; ++i)
#pragma unroll
            for (int e = 0; e < 4; ++e) {
                acc[i][j][e] += bj;
                float v = acc[i][j][e];
                s += v; s2 += v * v;
            }
        s  += __shfl_xor(s, 16);  s  += __shfl_xor(s, 32);
        s2 += __shfl_xor(s2, 16); s2 += __shfl_xor(s2, 32);
        sj[j] = s; s2j[j] = s2;
    }
#pragma unroll
    for (int i = 0; i < 4; ++i)
#pragma unroll
        for (int e = 0; e < 4; ++e) {
            size_t row = m0 + wr * 64 + i * 16 + q * 4 + e;
#pragma unroll
            for (int j = 0; j < 4; ++j)
                C[row * 256 + wc * 64 + j * 16 + r] = f2bf(acc[i][j][e]);
        }
    if (q == 0) {
        int slot = blockIdx.x & (NSLOT - 1);
#pragma unroll
        for (int j = 0; j < 4; ++j) {
            int col = wc * 64 + j * 16 + r;
            atomicAdd(&stat_partials[slot * 512 + col], sj[j]);
            atomicAdd(&stat_partials[slot * 512 + 256 + col], s2j[j]);
        }
    }
}

// ---------- readout heads (BN prologue for layer-3 outer BN) ----------
__global__ __launch_bounds__(256) void head_kernel(const float* __restrict__ ts0,
                                                   const float* __restrict__ ts1,
                                                   const unsigned short* __restrict__ p3,
                                                   const unsigned short* __restrict__ Z3b,
                                                   const float* __restrict__ partials,
                                                   const float* __restrict__ g,
                                                   const float* __restrict__ b,
                                                   float invM,
                                                   const float* __restrict__ p0w,
                                                   const float* __restrict__ p0b,
                                                   const float* __restrict__ phw,
                                                   const float* __restrict__ phb,
                                                   float* __restrict__ out) {
    __shared__ float sc_lds[256], sh_lds[256];
    int t = blockIdx.x, d = threadIdx.x;
    bn_prologue(d, partials, g, b, invM, sc_lds, sh_lds);
    __syncthreads();
    float acc[10];
#pragma unroll
    for (int o = 0; o < 10; ++o) acc[o] = 0.f;
    if (d < 128) {
        float v = ts0[t * 128 + d];
#pragma unroll
        for (int o = 0; o < 10; ++o) acc[o] += v * p0w[d * 10 + o];
    }
    {
        float v = ts1[t * 256 + d];
#pragma unroll
        for (int o = 0; o < 10; ++o) acc[o] += v * phw[d * 10 + o];
    }
    {
        float v = bf2f(p3[t * 256 + d]);
#pragma unroll
        for (int o = 0; o < 10; ++o) acc[o] += v * phw[2560 + d * 10 + o];
    }
    {
        float v = sc_lds[d] * bf2f(Z3b[t * 256 + d]) + sh_lds[d];
        v = v > 0.f ? v : 0.f;
#pragma unroll
        for (int o = 0; o < 10; ++o) acc[o] += v * phw[5120 + d * 10 + o];
    }
    __shared__ float red[256];
    for (int o = 0; o < 10; ++o) {
        red[d] = acc[o];
        __syncthreads();
        for (int s = 128; s > 0; s >>= 1) {
            if (d < s) red[d] += red[d + s];
            __syncthreads();
        }
        if (d == 0) out[t * 10 + o] = red[0] + p0b[o] + phb[o] + phb[10 + o] + phb[20 + o];
        __syncthreads();
    }
}

extern "C" void kernel_launch(void* const* d_in, const int* in_sizes, int n_in,
                              void* d_out, int out_size, void* d_ws, size_t ws_size,
                              hipStream_t stream) {
    const float* x       = (const float*)d_in[0];
    const float* l1_w1   = (const float*)d_in[7];
    const float* l1_b1   = (const float*)d_in[8];
    const float* l1_bn1g = (const float*)d_in[9];
    const float* l1_bn1b = (const float*)d_in[10];
    const float* l1_w2   = (const float*)d_in[11];
    const float* l1_b2   = (const float*)d_in[12];
    const float* l1_bng  = (const float*)d_in[13];
    const float* l1_bnb  = (const float*)d_in[14];
    const float* lw1     = (const float*)d_in[15];
    const float* lb1     = (const float*)d_in[16];
    const float* lbn1g   = (const float*)d_in[17];
    const float* lbn1b   = (const float*)d_in[18];
    const float* lw2     = (const float*)d_in[19];
    const float* lb2     = (const float*)d_in[20];
    const float* lbng    = (const float*)d_in[21];
    const float* lbnb    = (const float*)d_in[22];
    const float* pred0_w = (const float*)d_in[23];
    const float* pred0_b = (const float*)d_in[24];
    const float* predh_w = (const float*)d_in[25];
    const float* predh_b = (const float*)d_in[26];
    float* out = (float*)d_out;

    uint8_t* wsb = (uint8_t*)d_ws;
    unsigned short* pooled1 = (unsigned short*)(wsb);                          // 16 MB
    unsigned short* Z1      = (unsigned short*)(wsb + (16ull << 20));          // 32 MB
    unsigned short* Z2      = (unsigned short*)(wsb + (48ull << 20));          // 32 MB
    unsigned short* pooled2 = (unsigned short*)(wsb + (80ull << 20));          // 4 MB
    unsigned short* Z2a     = (unsigned short*)(wsb + (84ull << 20));          // 4 MB
    unsigned short* Z2b     = (unsigned short*)(wsb + (88ull << 20));          // 4 MB
    unsigned short* pooled3 = (unsigned short*)(wsb + (92ull << 20));          // 128 KB
    unsigned short* Z3a     = (unsigned short*)(wsb + (92ull << 20) + 131072); // 128 KB
    unsigned short* Z3b     = (unsigned short*)(wsb + (92ull << 20) + 262144); // 128 KB
    unsigned short* Wt      = (unsigned short*)(wsb + (93ull << 20));          // 720 KB
    // zeroed region: ts0 [256*128] f32, ts1 [256*256] f32, stats 6 x [8][512] f32
    float* zbase = (float*)(wsb + (94ull << 20));
    float* ts0   = zbase;
    float* ts1   = zbase + 32768;
    float* stats = zbase + 32768 + 65536;
    auto SP = [&](int i) { return stats + i * (NSLOT * 512); };
    size_t zbytes = (32768 + 65536 + 6 * NSLOT * 512) * sizeof(float);

    hipMemsetAsync(zbase, 0, zbytes, stream);
    prep_weights<<<1408, 256, 0, stream>>>(l1_w1, l1_w2, lw1, lw2, Wt);

    // layer 1
    pool8_128<<<N1 / 8, 256, 0, stream>>>(x, pooled1, ts0);
    mfma_gemm<128, false, 128><<<N1 / 128, 512, 0, stream>>>(
        pooled1, nullptr, nullptr, nullptr, 0.f, Wt, l1_b1, Z1, SP(0));
    mfma_gemm<256, true, 128><<<N1 / 128, 512, 0, stream>>>(
        Z1, SP(0), l1_bn1g, l1_bn1b, 1.f / N1, Wt + 32768, l1_b2, Z2, SP(1));
    pool_bn_relu<8, true><<<N2 / 8, 256, 0, stream>>>(
        Z2, SP(1), l1_bng, l1_bnb, 1.f / N1, pooled2, ts1);

    // layer 2
    mfma_gemm<256, false, 64><<<N2 / 64, 256, 0, stream>>>(
        pooled2, nullptr, nullptr, nullptr, 0.f, Wt + 98304, lb1, Z2a, SP(2));
    mfma_gemm<256, true, 64><<<N2 / 64, 256, 0, stream>>>(
        Z2a, SP(2), lbn1g, lbn1b, 1.f / N2, Wt + 163840, lb2, Z2b, SP(3));
    pool_bn_relu<32, false><<<NB / 8, 256, 0, stream>>>(
        Z2b, SP(3), lbng, lbnb, 1.f / N2, pooled3, nullptr);

    // layer 3 (weight index 1)
    mfma_gemm<256, false, 64><<<NB / 64, 256, 0, stream>>>(
        pooled3, nullptr, nullptr, nullptr, 0.f, Wt + 229376, lb1 + 256, Z3a, SP(4));
    mfma_gemm<256, true, 64><<<NB / 64, 256, 0, stream>>>(
        Z3a, SP(4), lbn1g + 256, lbn1b + 256, 1.f / NB, Wt + 294912, lb2 + 256, Z3b, SP(5));

    // readout
    head_kernel<<<NB, 256, 0, stream>>>(ts0, ts1, pooled3, Z3b, SP(5),
                                        lbng + 256, lbnb + 256, 1.f / NB,
                                        pred0_w, pred0_b, predh_w, predh_b, out);
}

// Round 4
// 191.386 us; speedup vs baseline: 1.0290x; 1.0290x over previous
//
#include <hip/hip_runtime.h>
#include <hip/hip_bf16.h>

// TreeCNN on MI355X — bf16 MFMA, pools fused into GEMM A-stages.
// B=256 trees, 2048->256->32->1 (arities 8,8,32), D_IN=128, HID=256, OUT=10.
// 10 dispatches: memset, prep_weights, G1A(x-pool8+ts0), G1B(BN), G2A(BN+pool8+ts1),
// G2B(BN), pool32(BN), G3A, G3B(BN), head(BN).

#define N0 (256*2048)
#define N1 (256*256)
#define N2 (256*32)
#define NB 256
#define BN_EPS 1e-5f
#define NSLOT 8

typedef __attribute__((ext_vector_type(8))) __bf16 bf16x8;
typedef __attribute__((ext_vector_type(8))) unsigned short u16x8;
typedef __attribute__((ext_vector_type(4))) unsigned short u16x4;
typedef __attribute__((ext_vector_type(4))) float f32x4;

__device__ inline float bf2f(unsigned short b) {
    unsigned u = ((unsigned)b) << 16;
    float f; __builtin_memcpy(&f, &u, 4); return f;
}
__device__ inline unsigned short f2bf(float f) {
    unsigned u; __builtin_memcpy(&u, &f, 4);
    u += 0x7fff + ((u >> 16) & 1);
    return (unsigned short)(u >> 16);
}

// ---------- weights: transpose + f32->bf16, Wt[n][k] ----------
__global__ __launch_bounds__(256) void prep_weights(const float* __restrict__ l1_w1,
                                                    const float* __restrict__ l1_w2,
                                                    const float* __restrict__ lw1,
                                                    const float* __restrict__ lw2,
                                                    unsigned short* __restrict__ Wt) {
    int idx = blockIdx.x * 256 + threadIdx.x;
    if (idx >= 360448) return;
    float v;
    if (idx < 32768) {                       // l1_w1 [128,256] -> [256][128]
        int n = idx >> 7, k = idx & 127;
        v = l1_w1[k * 256 + n];
    } else if (idx < 98304) {                // l1_w2 [256,256]
        int j = idx - 32768, n = j >> 8, k = j & 255;
        v = l1_w2[k * 256 + n];
    } else if (idx < 163840) {               // lw1[0]
        int j = idx - 98304, n = j >> 8, k = j & 255;
        v = lw1[k * 256 + n];
    } else if (idx < 229376) {               // lw2[0]
        int j = idx - 163840, n = j >> 8, k = j & 255;
        v = lw2[k * 256 + n];
    } else if (idx < 294912) {               // lw1[1]
        int j = idx - 229376, n = j >> 8, k = j & 255;
        v = lw1[65536 + k * 256 + n];
    } else {                                 // lw2[1]
        int j = idx - 294912, n = j >> 8, k = j & 255;
        v = lw2[65536 + k * 256 + n];
    }
    Wt[idx] = f2bf(v);
}

// ---------- BN finalize prologue helper ----------
__device__ inline void bn_prologue(int tid, const float* __restrict__ partials,
                                   const float* __restrict__ g, const float* __restrict__ b,
                                   float invM, float* sc_lds, float* sh_lds) {
    if (tid < 256) {
        float s = 0.f, s2 = 0.f;
#pragma unroll
        for (int k = 0; k < NSLOT; ++k) {
            s  += partials[k * 512 + tid];
            s2 += partials[k * 512 + 256 + tid];
        }
        float mean = s * invM;
        float var = s2 * invM - mean * mean;
        float sc = g[tid] * rsqrtf(var + BN_EPS);
        sc_lds[tid] = sc;
        sh_lds[tid] = b[tid] - mean * sc;
    }
}

// ---------- G1A: x -> pool8(f32) -> [A-tile] @ W1 -> Z1; fused ts0 + stats ----------
// Block: 128 pooled rows x 256 cols, 512 thr (8 waves: wr=wave>>2, wc=wave&3). K=128.
__global__ __launch_bounds__(512) void gemm1_fused(const float* __restrict__ x,
                                                   const unsigned short* __restrict__ Wt,
                                                   const float* __restrict__ bias,
                                                   unsigned short* __restrict__ Z1,
                                                   float* __restrict__ stat_partials,
                                                   float* __restrict__ ts0) {
    constexpr int LDA = 136, LDB = 72;       // dword strides 68,36 == 4 mod 32 -> 2-way (free)
    __shared__ unsigned short Asb[128 * LDA];
    __shared__ unsigned short Bsb[256 * LDB];
    const int tid = threadIdx.x;
    const int c4 = tid & 31, rg = tid >> 5;  // rg 0..15, 8 rows each
    const int m0 = blockIdx.x * 128;
    const int tree = blockIdx.x >> 1;        // 256 pooled rows per tree
    // pooling pass: 8 rows x 8 children x f32x4
    f32x4 colp = {0.f, 0.f, 0.f, 0.f};
#pragma unroll
    for (int i = 0; i < 8; ++i) {
        int row = rg * 8 + i;
        const f32x4* xp = reinterpret_cast<const f32x4*>(x + (size_t)(m0 + row) * 1024 + c4 * 4);
        f32x4 s = {0.f, 0.f, 0.f, 0.f};
#pragma unroll
        for (int c = 0; c < 8; ++c) s += xp[c * 32];
        u16x4 o;
#pragma unroll
        for (int e = 0; e < 4; ++e) o[e] = f2bf(s[e]);
        *reinterpret_cast<u16x4*>(&Asb[row * LDA + c4 * 4]) = o;
        colp += s;
    }
#pragma unroll
    for (int e = 0; e < 4; ++e) atomicAdd(&ts0[tree * 128 + c4 * 4 + e], colp[e]);

    const int wave = tid >> 6, lane = tid & 63;
    const int q = lane >> 4, r = lane & 15;
    const int wc = wave & 3, wr = wave >> 2;
    f32x4 acc[4][4];
#pragma unroll
    for (int i = 0; i < 4; ++i)
#pragma unroll
        for (int j = 0; j < 4; ++j) acc[i][j] = (f32x4){0.f, 0.f, 0.f, 0.f};

#pragma unroll
    for (int s2 = 0; s2 < 2; ++s2) {         // K-halves of 64
#pragma unroll
        for (int i = 0; i < 4; ++i) {        // stage B: 256 n x 64 k
            int v = tid + i * 512;
            int n = v >> 3, kc = v & 7;
            u16x8 d = *reinterpret_cast<const u16x8*>(Wt + (size_t)n * 128 + s2 * 64 + kc * 8);
            *reinterpret_cast<u16x8*>(&Bsb[n * LDB + kc * 8]) = d;
        }
        __syncthreads();                     // first iter also guards Asb pooling writes
#pragma unroll
        for (int s = 0; s < 2; ++s) {
            bf16x8 a[4], b[4];
#pragma unroll
            for (int i = 0; i < 4; ++i)
                a[i] = *reinterpret_cast<const bf16x8*>(&Asb[(wr * 64 + i * 16 + r) * LDA + s2 * 64 + s * 32 + q * 8]);
#pragma unroll
            for (int j = 0; j < 4; ++j)
                b[j] = *reinterpret_cast<const bf16x8*>(&Bsb[(wc * 64 + j * 16 + r) * LDB + s * 32 + q * 8]);
#pragma unroll
            for (int i = 0; i < 4; ++i)
#pragma unroll
                for (int j = 0; j < 4; ++j)
                    acc[i][j] = __builtin_amdgcn_mfma_f32_16x16x32_bf16(a[i], b[j], acc[i][j], 0, 0, 0);
        }
        __syncthreads();
    }
    // epilogue: +bias, col stats, store. C/D: col=r, row=q*4+e per 16x16 frag.
    float sj[4], s2j[4];
#pragma unroll
    for (int j = 0; j < 4; ++j) {
        float bj = bias[wc * 64 + j * 16 + r];
        float s = 0.f, s2 = 0.f;
#pragma unroll
        for (int i = 0; i < 4; ++i)
#pragma unroll
            for (int e = 0; e < 4; ++e) {
                acc[i][j][e] += bj;
                float v = acc[i][j][e];
                s += v; s2 += v * v;
            }
        s  += __shfl_xor(s, 16);  s  += __shfl_xor(s, 32);
        s2 += __shfl_xor(s2, 16); s2 += __shfl_xor(s2, 32);
        sj[j] = s; s2j[j] = s2;
    }
#pragma unroll
    for (int i = 0; i < 4; ++i)
#pragma unroll
        for (int e = 0; e < 4; ++e) {
            size_t row = m0 + wr * 64 + i * 16 + q * 4 + e;
#pragma unroll
            for (int j = 0; j < 4; ++j)
                Z1[row * 256 + wc * 64 + j * 16 + r] = f2bf(acc[i][j][e]);
        }
    if (q == 0) {
        int slot = blockIdx.x & (NSLOT - 1);
#pragma unroll
        for (int j = 0; j < 4; ++j) {
            int col = wc * 64 + j * 16 + r;
            atomicAdd(&stat_partials[slot * 512 + col], sj[j]);
            atomicAdd(&stat_partials[slot * 512 + 256 + col], s2j[j]);
        }
    }
}

// ---------- G2A: Z2 -> BN+ReLU+pool8 -> [A] @ W2_1 -> Z2a; fused ts1 + stats ----------
// Block: 64 pooled rows x 256 cols, 256 thr (4 waves, wc=wave). K=256 (A full-K in LDS).
__global__ __launch_bounds__(256) void gemm2_fused(const unsigned short* __restrict__ Z2,
                                                   const float* __restrict__ partials_in,
                                                   const float* __restrict__ bn_g,
                                                   const float* __restrict__ bn_b,
                                                   float invM,
                                                   const unsigned short* __restrict__ Wt2,
                                                   const float* __restrict__ bias,
                                                   unsigned short* __restrict__ Z2a,
                                                   float* __restrict__ stat_partials,
                                                   float* __restrict__ ts1) {
    constexpr int LDA = 264, LDB = 72;       // dword strides 132,36 == 4 mod 32
    __shared__ unsigned short Asb[64 * LDA];
    __shared__ unsigned short Bsb[256 * LDB];
    __shared__ float sc_lds[256], sh_lds[256];
    const int tid = threadIdx.x;
    bn_prologue(tid, partials_in, bn_g, bn_b, invM, sc_lds, sh_lds);
    __syncthreads();
    const int c8 = tid & 31, rg = tid >> 5;  // rg 0..7, 8 rows each
    const int m0 = blockIdx.x * 64;
    const int d0 = c8 * 8;
    float sc[8], sh[8], colp[8];
#pragma unroll
    for (int e = 0; e < 8; ++e) { sc[e] = sc_lds[d0 + e]; sh[e] = sh_lds[d0 + e]; colp[e] = 0.f; }
#pragma unroll
    for (int i = 0; i < 8; ++i) {
        int row = rg * 8 + i;
        float s[8];
#pragma unroll
        for (int e = 0; e < 8; ++e) s[e] = 0.f;
#pragma unroll
        for (int c = 0; c < 8; ++c) {
            u16x8 z = *reinterpret_cast<const u16x8*>(Z2 + ((size_t)(m0 + row) * 8 + c) * 256 + d0);
#pragma unroll
            for (int e = 0; e < 8; ++e) {
                float f = sc[e] * bf2f(z[e]) + sh[e];
                s[e] += f > 0.f ? f : 0.f;
            }
        }
        u16x8 o;
#pragma unroll
        for (int e = 0; e < 8; ++e) { o[e] = f2bf(s[e]); colp[e] += s[e]; }
        *reinterpret_cast<u16x8*>(&Asb[row * LDA + d0]) = o;
    }
    {
        int tree = blockIdx.x * 2 + (rg >> 2);   // 32 pooled rows per tree
#pragma unroll
        for (int e = 0; e < 8; ++e) atomicAdd(&ts1[tree * 256 + d0 + e], colp[e]);
    }
    const int wave = tid >> 6, lane = tid & 63;
    const int q = lane >> 4, r = lane & 15;
    const int wc = wave;
    f32x4 acc[4][4];
#pragma unroll
    for (int i = 0; i < 4; ++i)
#pragma unroll
        for (int j = 0; j < 4; ++j) acc[i][j] = (f32x4){0.f, 0.f, 0.f, 0.f};

    for (int kt = 0; kt < 4; ++kt) {         // K-tiles of 64
#pragma unroll
        for (int i = 0; i < 8; ++i) {
            int v = tid + i * 256;
            int n = v >> 3, kc = v & 7;
            u16x8 d = *reinterpret_cast<const u16x8*>(Wt2 + (size_t)n * 256 + kt * 64 + kc * 8);
            *reinterpret_cast<u16x8*>(&Bsb[n * LDB + kc * 8]) = d;
        }
        __syncthreads();
#pragma unroll
        for (int s = 0; s < 2; ++s) {
            bf16x8 a[4], b[4];
#pragma unroll
            for (int i = 0; i < 4; ++i)
                a[i] = *reinterpret_cast<const bf16x8*>(&Asb[(i * 16 + r) * LDA + kt * 64 + s * 32 + q * 8]);
#pragma unroll
            for (int j = 0; j < 4; ++j)
                b[j] = *reinterpret_cast<const bf16x8*>(&Bsb[(wc * 64 + j * 16 + r) * LDB + s * 32 + q * 8]);
#pragma unroll
            for (int i = 0; i < 4; ++i)
#pragma unroll
                for (int j = 0; j < 4; ++j)
                    acc[i][j] = __builtin_amdgcn_mfma_f32_16x16x32_bf16(a[i], b[j], acc[i][j], 0, 0, 0);
        }
        __syncthreads();
    }
    float sj[4], s2j[4];
#pragma unroll
    for (int j = 0; j < 4; ++j) {
        float bj = bias[wc * 64 + j * 16 + r];
        float s = 0.f, s2 = 0.f;
#pragma unroll
        for (int i = 0; i < 4; ++i)
#pragma unroll
            for (int e = 0; e < 4; ++e) {
                acc[i][j][e] += bj;
                float v = acc[i][j][e];
                s += v; s2 += v * v;
            }
        s  += __shfl_xor(s, 16);  s  += __shfl_xor(s, 32);
        s2 += __shfl_xor(s2, 16); s2 += __shfl_xor(s2, 32);
        sj[j] = s; s2j[j] = s2;
    }
#pragma unroll
    for (int i = 0; i < 4; ++i)
#pragma unroll
        for (int e = 0; e < 4; ++e) {
            size_t row = m0 + i * 16 + q * 4 + e;
#pragma unroll
            for (int j = 0; j < 4; ++j)
                Z2a[row * 256 + wc * 64 + j * 16 + r] = f2bf(acc[i][j][e]);
        }
    if (q == 0) {
        int slot = blockIdx.x & (NSLOT - 1);
#pragma unroll
        for (int j = 0; j < 4; ++j) {
            int col = wc * 64 + j * 16 + r;
            atomicAdd(&stat_partials[slot * 512 + col], sj[j]);
            atomicAdd(&stat_partials[slot * 512 + 256 + col], s2j[j]);
        }
    }
}

// ---------- generic MFMA GEMM (used for G1B, G2B, G3A, G3B) ----------
template <int KD, bool BN_A, int BM>
__global__ __launch_bounds__(BM * 4) void mfma_gemm(const unsigned short* __restrict__ A,
                                                    const float* __restrict__ partials_in,
                                                    const float* __restrict__ bn_g,
                                                    const float* __restrict__ bn_b,
                                                    float invM,
                                                    const unsigned short* __restrict__ Wt,
                                                    const float* __restrict__ bias,
                                                    unsigned short* __restrict__ C,
                                                    float* __restrict__ stat_partials) {
    constexpr int LDA = 72;
    constexpr int NT = BM * 4;
    __shared__ unsigned short Asb[BM * LDA];
    __shared__ unsigned short Bsb[256 * LDA];
    __shared__ float sc_lds[256], sh_lds[256];
    const int tid = threadIdx.x;
    if (BN_A) {
        bn_prologue(tid, partials_in, bn_g, bn_b, invM, sc_lds, sh_lds);
        __syncthreads();
    }
    const int m0 = blockIdx.x * BM;
    const int wave = tid >> 6, lane = tid & 63;
    const int q = lane >> 4, r = lane & 15;
    const int wc = wave & 3, wr = wave >> 2;

    f32x4 acc[4][4];
#pragma unroll
    for (int i = 0; i < 4; ++i)
#pragma unroll
        for (int j = 0; j < 4; ++j) acc[i][j] = (f32x4){0.f, 0.f, 0.f, 0.f};

    for (int k0 = 0; k0 < KD; k0 += 64) {
#pragma unroll
        for (int i = 0; i < 2; ++i) {
            int v = tid + i * NT;
            int row = v >> 3, kc = v & 7;
            u16x8 d = *reinterpret_cast<const u16x8*>(A + (size_t)(m0 + row) * KD + k0 + kc * 8);
            if (BN_A) {
                u16x8 o;
#pragma unroll
                for (int e = 0; e < 8; ++e) {
                    int k = k0 + kc * 8 + e;
                    float f = sc_lds[k] * bf2f(d[e]) + sh_lds[k];
                    o[e] = f2bf(f > 0.f ? f : 0.f);
                }
                d = o;
            }
            *reinterpret_cast<u16x8*>(&Asb[row * LDA + kc * 8]) = d;
        }
#pragma unroll
        for (int i = 0; i < 2048 / NT; ++i) {
            int v = tid + i * NT;
            int n = v >> 3, kc = v & 7;
            u16x8 d = *reinterpret_cast<const u16x8*>(Wt + (size_t)n * KD + k0 + kc * 8);
            *reinterpret_cast<u16x8*>(&Bsb[n * LDA + kc * 8]) = d;
        }
        __syncthreads();
#pragma unroll
        for (int s = 0; s < 2; ++s) {
            bf16x8 a[4], b[4];
#pragma unroll
            for (int i = 0; i < 4; ++i)
                a[i] = *reinterpret_cast<const bf16x8*>(&Asb[(wr * 64 + i * 16 + r) * LDA + s * 32 + q * 8]);
#pragma unroll
            for (int j = 0; j < 4; ++j)
                b[j] = *reinterpret_cast<const bf16x8*>(&Bsb[(wc * 64 + j * 16 + r) * LDA + s * 32 + q * 8]);
#pragma unroll
            for (int i = 0; i < 4; ++i)
#pragma unroll
                for (int j = 0; j < 4; ++j)
                    acc[i][j] = __builtin_amdgcn_mfma_f32_16x16x32_bf16(a[i], b[j], acc[i][j], 0, 0, 0);
        }
        __syncthreads();
    }
    float sj[4], s2j[4];
#pragma unroll
    for (int j = 0; j < 4; ++j) {
        float bj = bias[wc * 64 + j * 16 + r];
        float s = 0.f, s2 = 0.f;
#pragma unroll
        for (int i = 0; i < 4; ++i)
#pragma unroll
            for (int e = 0; e < 4; ++e) {
                acc[i][j][e] += bj;
                float v = acc[i][j][e];
                s += v; s2 += v * v;
            }
        s  += __shfl_xor(s, 16);  s  += __shfl_xor(s, 32);
        s2 += __shfl_xor(s2, 16); s2 += __shfl_xor(s2, 32);
        sj[j] = s; s2j[j] = s2;
    }
#pragma unroll
    for (int i = 0; i < 4; ++i)
#pragma unroll
        for (int e = 0; e < 4; ++e) {
            size_t row = m0 + wr * 64 + i * 16 + q * 4 + e;
#pragma unroll
            for (int j = 0; j < 4; ++j)
                C[row * 256 + wc * 64 + j * 16 + r] = f2bf(acc[i][j][e]);
        }
    if (q == 0) {
        int slot = blockIdx.x & (NSLOT - 1);
#pragma unroll
        for (int j = 0; j < 4; ++j) {
            int col = wc * 64 + j * 16 + r;
            atomicAdd(&stat_partials[slot * 512 + col], sj[j]);
            atomicAdd(&stat_partials[slot * 512 + 256 + col], s2j[j]);
        }
    }
}

// ---------- pool32 with BN prologue (Z2b -> pooled3) ----------
__global__ __launch_bounds__(256) void pool_bn_relu32(const unsigned short* __restrict__ Z,
                                                      const float* __restrict__ partials,
                                                      const float* __restrict__ g,
                                                      const float* __restrict__ b,
                                                      float invM,
                                                      unsigned short* __restrict__ out) {
    __shared__ float sc_lds[256], sh_lds[256];
    int tid = threadIdx.x;
    bn_prologue(tid, partials, g, b, invM, sc_lds, sh_lds);
    __syncthreads();
    int c8 = tid & 31, pl = tid >> 5;
    size_t p = (size_t)blockIdx.x * 8 + pl;
    int d0 = c8 * 8;
    float sc[8], sh[8], s[8];
#pragma unroll
    for (int e = 0; e < 8; ++e) { sc[e] = sc_lds[d0 + e]; sh[e] = sh_lds[d0 + e]; s[e] = 0.f; }
#pragma unroll
    for (int gi = 0; gi < 32; ++gi) {
        u16x8 z = *reinterpret_cast<const u16x8*>(Z + (p * 32 + gi) * 256 + d0);
#pragma unroll
        for (int e = 0; e < 8; ++e) {
            float f = sc[e] * bf2f(z[e]) + sh[e];
            s[e] += f > 0.f ? f : 0.f;
        }
    }
    u16x8 o;
#pragma unroll
    for (int e = 0; e < 8; ++e) o[e] = f2bf(s[e]);
    *reinterpret_cast<u16x8*>(out + p * 256 + d0) = o;
}

// ---------- readout heads (BN prologue for layer-3 outer BN) ----------
__global__ __launch_bounds__(256) void head_kernel(const float* __restrict__ ts0,
                                                   const float* __restrict__ ts1,
                                                   const unsigned short* __restrict__ p3,
                                                   const unsigned short* __restrict__ Z3b,
                                                   const float* __restrict__ partials,
                                                   const float* __restrict__ g,
                                                   const float* __restrict__ b,
                                                   float invM,
                                                   const float* __restrict__ p0w,
                                                   const float* __restrict__ p0b,
                                                   const float* __restrict__ phw,
                                                   const float* __restrict__ phb,
                                                   float* __restrict__ out) {
    __shared__ float sc_lds[256], sh_lds[256];
    int t = blockIdx.x, d = threadIdx.x;
    bn_prologue(d, partials, g, b, invM, sc_lds, sh_lds);
    __syncthreads();
    float acc[10];
#pragma unroll
    for (int o = 0; o < 10; ++o) acc[o] = 0.f;
    if (d < 128) {
        float v = ts0[t * 128 + d];
#pragma unroll
        for (int o = 0; o < 10; ++o) acc[o] += v * p0w[d * 10 + o];
    }
    {
        float v = ts1[t * 256 + d];
#pragma unroll
        for (int o = 0; o < 10; ++o) acc[o] += v * phw[d * 10 + o];
    }
    {
        float v = bf2f(p3[t * 256 + d]);
#pragma unroll
        for (int o = 0; o < 10; ++o) acc[o] += v * phw[2560 + d * 10 + o];
    }
    {
        float v = sc_lds[d] * bf2f(Z3b[t * 256 + d]) + sh_lds[d];
        v = v > 0.f ? v : 0.f;
#pragma unroll
        for (int o = 0; o < 10; ++o) acc[o] += v * phw[5120 + d * 10 + o];
    }
    __shared__ float red[256];
    for (int o = 0; o < 10; ++o) {
        red[d] = acc[o];
        __syncthreads();
        for (int s = 128; s > 0; s >>= 1) {
            if (d < s) red[d] += red[d + s];
            __syncthreads();
        }
        if (d == 0) out[t * 10 + o] = red[0] + p0b[o] + phb[o] + phb[10 + o] + phb[20 + o];
        __syncthreads();
    }
}

extern "C" void kernel_launch(void* const* d_in, const int* in_sizes, int n_in,
                              void* d_out, int out_size, void* d_ws, size_t ws_size,
                              hipStream_t stream) {
    const float* x       = (const float*)d_in[0];
    const float* l1_w1   = (const float*)d_in[7];
    const float* l1_b1   = (const float*)d_in[8];
    const float* l1_bn1g = (const float*)d_in[9];
    const float* l1_bn1b = (const float*)d_in[10];
    const float* l1_w2   = (const float*)d_in[11];
    const float* l1_b2   = (const float*)d_in[12];
    const float* l1_bng  = (const float*)d_in[13];
    const float* l1_bnb  = (const float*)d_in[14];
    const float* lw1     = (const float*)d_in[15];
    const float* lb1     = (const float*)d_in[16];
    const float* lbn1g   = (const float*)d_in[17];
    const float* lbn1b   = (const float*)d_in[18];
    const float* lw2     = (const float*)d_in[19];
    const float* lb2     = (const float*)d_in[20];
    const float* lbng    = (const float*)d_in[21];
    const float* lbnb    = (const float*)d_in[22];
    const float* pred0_w = (const float*)d_in[23];
    const float* pred0_b = (const float*)d_in[24];
    const float* predh_w = (const float*)d_in[25];
    const float* predh_b = (const float*)d_in[26];
    float* out = (float*)d_out;

    uint8_t* wsb = (uint8_t*)d_ws;
    unsigned short* Z1      = (unsigned short*)(wsb + (16ull << 20));          // 32 MB
    unsigned short* Z2      = (unsigned short*)(wsb + (48ull << 20));          // 32 MB
    unsigned short* Z2a     = (unsigned short*)(wsb + (84ull << 20));          // 4 MB
    unsigned short* Z2b     = (unsigned short*)(wsb + (88ull << 20));          // 4 MB
    unsigned short* pooled3 = (unsigned short*)(wsb + (92ull << 20));          // 128 KB
    unsigned short* Z3a     = (unsigned short*)(wsb + (92ull << 20) + 131072); // 128 KB
    unsigned short* Z3b     = (unsigned short*)(wsb + (92ull << 20) + 262144); // 128 KB
    unsigned short* Wt      = (unsigned short*)(wsb + (93ull << 20));          // 720 KB
    float* zbase = (float*)(wsb + (94ull << 20));
    float* ts0   = zbase;                    // 256*128
    float* ts1   = zbase + 32768;            // 256*256
    float* stats = zbase + 32768 + 65536;    // 6 x [NSLOT][512]
    auto SP = [&](int i) { return stats + i * (NSLOT * 512); };
    size_t zbytes = (32768 + 65536 + 6 * NSLOT * 512) * sizeof(float);

    hipMemsetAsync(zbase, 0, zbytes, stream);
    prep_weights<<<1408, 256, 0, stream>>>(l1_w1, l1_w2, lw1, lw2, Wt);

    // layer 1
    gemm1_fused<<<N1 / 128, 512, 0, stream>>>(x, Wt, l1_b1, Z1, SP(0), ts0);
    mfma_gemm<256, true, 128><<<N1 / 128, 512, 0, stream>>>(
        Z1, SP(0), l1_bn1g, l1_bn1b, 1.f / N1, Wt + 32768, l1_b2, Z2, SP(1));

    // layer 2 (A = pool8 of relu(bn(Z2)))
    gemm2_fused<<<N2 / 64, 256, 0, stream>>>(
        Z2, SP(1), l1_bng, l1_bnb, 1.f / N1, Wt + 98304, lb1, Z2a, SP(2), ts1);
    mfma_gemm<256, true, 64><<<N2 / 64, 256, 0, stream>>>(
        Z2a, SP(2), lbn1g, lbn1b, 1.f / N2, Wt + 163840, lb2, Z2b, SP(3));
    pool_bn_relu32<<<NB / 8, 256, 0, stream>>>(Z2b, SP(3), lbng, lbnb, 1.f / N2, pooled3);

    // layer 3 (weight index 1)
    mfma_gemm<256, false, 64><<<NB / 64, 256, 0, stream>>>(
        pooled3, nullptr, nullptr, nullptr, 0.f, Wt + 229376, lb1 + 256, Z3a, SP(4));
    mfma_gemm<256, true, 64><<<NB / 64, 256, 0, stream>>>(
        Z3a, SP(4), lbn1g + 256, lbn1b + 256, 1.f / NB, Wt + 294912, lb2 + 256, Z3b, SP(5));

    // readout
    head_kernel<<<NB, 256, 0, stream>>>(ts0, ts1, pooled3, Z3b, SP(5),
                                        lbng + 256, lbnb + 256, 1.f / NB,
                                        pred0_w, pred0_b, predh_w, predh_b, out);
}